// Round 8
// baseline (45.944 us; speedup 1.0000x reference)
//
#include <hip/hip_runtime.h>

#define IN_F   8192
#define OUT_F  8192
#define N_BLK  (OUT_F / 2)     // 4096 blocks in kernel 1 (2 rows/block)
#define W_THRESH 50.0f
#define INHIB  0.5f

typedef float f32x4 __attribute__((ext_vector_type(4)));

// ---------------------------------------------------------------------------
// Kernel 1: current[o] = sum_i spike[i] * (state[o][i] > 50), per-row spike
// decision, and a per-block spike partial for kernel 2.
// A/B this round: each ROW is split across 2 waves (16 f32x4 spike fragments
// per lane -> 64 VGPR preload instead of 128), launch_bounds(256,5) forces
// VGPR <= 102 -> 5 waves/SIMD = 20 waves/CU (vs 12 in round 7). Inner loop
// stays a pure global stream (round-7 A/B: reg-preload beat LDS by 1.2 us).
// Block: 4 waves = 2 rows x 2 half-rows.
// ---------------------------------------------------------------------------
__global__ __launch_bounds__(256, 5) void snn_current_kernel(
    const float* __restrict__ spike,
    const float* __restrict__ states,
    const float* __restrict__ v_mem,
    const float* __restrict__ v_th,
    const float* __restrict__ noise,
    float* __restrict__ current,        // ws[0..8191]
    float* __restrict__ out_spikes,     // out[0..8191]
    float* __restrict__ block_partial)  // ws[8192..12287]
{
    __shared__ float s_half[4];         // per-wave half-row sums
    __shared__ float s_f[2];            // per-row spike flags

    const int tid  = threadIdx.x;
    const int wave = tid >> 6;          // 0..3
    const int lane = tid & 63;
    const int rloc = wave >> 1;         // 0..1 local row
    const int half = wave & 1;          // 0..1 half of the row
    const int row  = blockIdx.x * 2 + rloc;

    const f32x4* sp4  = (const f32x4*)spike;
    const f32x4* row4 = (const f32x4*)(states + (size_t)row * IN_F);
    const int base = half * 1024;       // f32x4 index of this half-row

    // preload this lane's 16 spike fragments (coalesced), static indexing
    f32x4 sp[16];
    #pragma unroll
    for (int j = 0; j < 16; ++j)
        sp[j] = sp4[base + j * 64 + lane];

    float acc = 0.0f;
    // pure global stream: 16 coalesced dwordx4 per lane
    #pragma unroll
    for (int j = 0; j < 16; ++j) {
        const f32x4 s = row4[base + j * 64 + lane];
        acc += (s[0] > W_THRESH) ? sp[j][0] : 0.0f;
        acc += (s[1] > W_THRESH) ? sp[j][1] : 0.0f;
        acc += (s[2] > W_THRESH) ? sp[j][2] : 0.0f;
        acc += (s[3] > W_THRESH) ? sp[j][3] : 0.0f;
    }

    // 64-lane butterfly reduction within each wave
    #pragma unroll
    for (int off = 32; off >= 1; off >>= 1)
        acc += __shfl_down(acc, off, 64);

    if (lane == 0) s_half[wave] = acc;
    __syncthreads();

    // threads 0,1: combine the two half-row sums for rows 0,1 and decide spike
    if (tid < 2) {
        const int r = blockIdx.x * 2 + tid;
        const float c = s_half[2 * tid] + s_half[2 * tid + 1];
        const float pot = v_mem[r] + c + noise[r];
        const float s = (pot >= v_th[r]) ? 1.0f : 0.0f;
        current[r]    = c;
        out_spikes[r] = s;
        s_f[tid]      = s;
    }
    __syncthreads();
    if (tid == 0)
        block_partial[blockIdx.x] = s_f[0] + s_f[1];
}

// ---------------------------------------------------------------------------
// Kernel 2: v_mem / v_th updates. Each block redundantly reduces the 4096
// per-block partials (16 KB, L2-resident; exact small integers) to get
// sum(spikes) without atomics, then handles its 256-element slice.
// out layout: [spikes(8192) | v_mem_new(8192) | v_th_new(8192)]
// ---------------------------------------------------------------------------
__global__ __launch_bounds__(256) void snn_update_kernel(
    const float* __restrict__ current,
    const float* __restrict__ v_mem,
    const float* __restrict__ v_th,
    const float* __restrict__ spikes,         // == out[0..8191]
    const float* __restrict__ block_partial,  // ws[8192..12287]
    float* __restrict__ out)
{
    __shared__ float s_part[4];

    const int tid = threadIdx.x;

    // sum of 4096 partials: 256 threads x 4 f32x4 each
    const f32x4* bp4 = (const f32x4*)block_partial;
    float local = 0.0f;
    #pragma unroll
    for (int k = 0; k < 4; ++k) {
        f32x4 v = bp4[tid + k * 256];
        local += v[0] + v[1] + v[2] + v[3];
    }
    #pragma unroll
    for (int off = 32; off >= 1; off >>= 1)
        local += __shfl_down(local, off, 64);
    if ((tid & 63) == 0) s_part[tid >> 6] = local;
    __syncthreads();

    const float total = s_part[0] + s_part[1] + s_part[2] + s_part[3];
    const float inhibition = total * INHIB;

    const int o = blockIdx.x * 256 + tid;
    const float s = spikes[o];
    const float vnew = (v_mem[o] - inhibition + current[o]) * (1.0f - s) * 0.5f;
    out[OUT_F + o] = vnew;
    float tnew = v_th[o] + (s - 0.1f) * 0.01f;
    tnew = fminf(fmaxf(tnew, 0.2f), 5.0f);
    out[2 * OUT_F + o] = tnew;
}

// ---------------------------------------------------------------------------
extern "C" void kernel_launch(void* const* d_in, const int* in_sizes, int n_in,
                              void* d_out, int out_size, void* d_ws, size_t ws_size,
                              hipStream_t stream)
{
    const float* spike  = (const float*)d_in[0];  // [1, 8192]
    const float* states = (const float*)d_in[1];  // [8192, 8192]
    const float* v_mem  = (const float*)d_in[2];  // [8192]
    const float* v_th   = (const float*)d_in[3];  // [8192]
    const float* noise  = (const float*)d_in[4];  // [8192]
    float* out = (float*)d_out;                   // [3 * 8192]

    float* current       = (float*)d_ws;          // ws[0..8191]
    float* block_partial = (float*)d_ws + OUT_F;  // ws[8192..12287]

    snn_current_kernel<<<N_BLK, 256, 0, stream>>>(
        spike, states, v_mem, v_th, noise, current, out, block_partial);
    snn_update_kernel<<<OUT_F / 256, 256, 0, stream>>>(
        current, v_mem, v_th, out, block_partial, out);
}